// Round 16
// baseline (132.803 us; speedup 1.0000x reference)
//
#include <hip/hip_runtime.h>

typedef unsigned short u16;
typedef unsigned int   u32;
typedef __bf16 bf16x8 __attribute__((ext_vector_type(8)));
typedef float  f32x4  __attribute__((ext_vector_type(4)));

// Geometry (fixed): b=32, h=w=56, C=192, NH=6, hd=32, WS=7, shift=3
// 2048 windows, 49 tokens (padded to 64).
// V16 = V15 + padded-row store predication: q/k stores skip tok>=49 (23 MB
//       fewer HBM writes/call). Stale k columns made safe via NaN-proof mask
//       select in attnproj (bf<-1e29 ? -1e30 : s+bf); stale q rows only feed
//       output rows that are never stored. v remains fully written (its rows
//       are an MFMA operand where NaN*0=NaN).

__device__ __forceinline__ u16 f2b(float f){
  return __builtin_bit_cast(u16, (__bf16)f);
}
__device__ __forceinline__ u32 pk2(float a, float b){
  return (u32)f2b(a) | ((u32)f2b(b) << 16);
}
__device__ __forceinline__ bf16x8 pack8(uint2 a, uint2 b){
  uint4 t; t.x = a.x; t.y = a.y; t.z = b.x; t.w = b.y;
  return __builtin_bit_cast(bf16x8, t);
}

__device__ __forceinline__ int coords_fn(int t){ return (t/7)*13 + (t%7); }
__device__ __forceinline__ int code_fn(int t, int wy, int wx){
  const int ty = t/7, tx = t%7;
  const int hp = wy*7 + ty, wp = wx*7 + tx;
  const int rh = (hp < 49) ? 0 : ((hp < 53) ? 1 : 2);
  const int rw = (wp < 49) ? 0 : ((wp < 53) ? 1 : 2);
  return rh*3 + rw;
}

// prep: wqF fragment-swizzled [36][6][64][8]; wpF [12][6][64][8];
//       biasC[cls][h][i][j] = rpb + (-100 shift mask) + (-1e30 j>=49)
__global__ __launch_bounds__(256) void prep_kernel(const float* __restrict__ qkvw,
                                                   const float* __restrict__ projw,
                                                   const float* __restrict__ rpb,
                                                   u16* __restrict__ wqF, u16* __restrict__ wpF,
                                                   float* __restrict__ biasC){
  const int i = blockIdx.x * 256 + threadIdx.x;   // 432*256 = 110592
  if (i < 13824){                                  // 36 tiles * 6 ks * 64 lanes
    const int f = i >> 6, l = i & 63;
    const int rt = f / 6, ks = f % 6;
    const int g = l >> 4, r = l & 15;
    const float* src = qkvw + (size_t)(rt*16 + r)*192 + ks*32 + 8*g;
    const float4 a = *reinterpret_cast<const float4*>(src);
    const float4 b = *reinterpret_cast<const float4*>(src + 4);
    uint4 w;
    w.x = pk2(a.x, a.y); w.y = pk2(a.z, a.w);
    w.z = pk2(b.x, b.y); w.w = pk2(b.z, b.w);
    *reinterpret_cast<uint4*>(wqF + (size_t)i*8) = w;
  }
  if (i < 4608){                                   // 12 tiles * 6 ks * 64 lanes
    const int f = i >> 6, l = i & 63;
    const int rt = f / 6, ks = f % 6;
    const int g = l >> 4, r = l & 15;
    const float* src = projw + (size_t)(rt*16 + r)*192 + ks*32 + 8*g;
    const float4 a = *reinterpret_cast<const float4*>(src);
    const float4 b = *reinterpret_cast<const float4*>(src + 4);
    uint4 w;
    w.x = pk2(a.x, a.y); w.y = pk2(a.z, a.w);
    w.z = pk2(b.x, b.y); w.w = pk2(b.z, b.w);
    *reinterpret_cast<uint4*>(wpF + (size_t)i*8) = w;
  }
  {
    const int cls = i / 27648, rem = i % 27648;
    const int h = rem / 4608, rem2 = rem % 4608;
    const int ii = rem2 / 72, j = rem2 % 72;
    const int wyR = (cls & 2) ? 7 : 0, wxR = (cls & 1) ? 7 : 0;
    float v = -1e30f;
    if (j < 49){
      const int icl = (ii > 48) ? 48 : ii;
      v = rpb[(coords_fn(icl) + coords_fn(48 - j))*6 + h];
      if (code_fn(icl, wyR, wxR) != code_fn(j, wyR, wxR)) v -= 100.0f;
    }
    biasC[i] = v;
  }
}

__device__ __forceinline__ bf16x8 wfrag(const u16* __restrict__ W, int rt, int ks, int lane){
  return *reinterpret_cast<const bf16x8*>(W + ((size_t)(rt*6 + ks)*64 + lane)*8);
}

// ---------------- A: roll + gather + QKV GEMM (2 windows/block) ----------------
__global__ __launch_bounds__(256, 2) void qkv_kernel(const float* __restrict__ x,
    const u16* __restrict__ wqF, const float* __restrict__ qb,
    u16* __restrict__ qG, u16* __restrict__ kG, u16* __restrict__ vG)
{
  __shared__ u16 XA[128][200];       // 2 windows x 64 tokens x 192ch
  const int wi0 = blockIdx.x * 2;    // windows wi0, wi0+1 (same bb, same wy)
  const int bb = wi0 >> 6, wy = (wi0 >> 3) & 7;
  const int tid = threadIdx.x;
  const int wave = tid >> 6, lane = tid & 63;
  const int g = lane >> 4, r = lane & 15;
  const f32x4 z4 = {0.f, 0.f, 0.f, 0.f};

  // gather: 2 halves x 6 chunks/thread of 16 bf16 (loads hoisted per half)
  #pragma unroll
  for (int half = 0; half < 2; ++half){
    float4 gv[6][2];
    int grow[6], gc8[6];
    #pragma unroll
    for (int i2 = 0; i2 < 6; ++i2){
      const int idx = half*1536 + i2*256 + tid;   // < 3072 = 128*24
      const int row = idx / 24, c8 = (idx % 24) * 8;
      grow[i2] = row; gc8[i2] = c8;
      const int rl = row & 63;
      const int wx = (wi0 + (row >> 6)) & 7;
      if (rl < 49){
        const int ty = rl / 7, tx = rl % 7;
        int sh = wy*7 + ty + 3; if (sh >= 56) sh -= 56;
        int sw = wx*7 + tx + 3; if (sw >= 56) sw -= 56;
        const float* src = x + (size_t)(((bb*56 + sh)*56 + sw))*192 + c8;
        gv[i2][0] = *reinterpret_cast<const float4*>(src);
        gv[i2][1] = *reinterpret_cast<const float4*>(src + 4);
      } else {
        gv[i2][0] = make_float4(0.f,0.f,0.f,0.f);
        gv[i2][1] = make_float4(0.f,0.f,0.f,0.f);
      }
    }
    #pragma unroll
    for (int i2 = 0; i2 < 6; ++i2){
      uint4 w;
      w.x = pk2(gv[i2][0].x, gv[i2][0].y);
      w.y = pk2(gv[i2][0].z, gv[i2][0].w);
      w.z = pk2(gv[i2][1].x, gv[i2][1].y);
      w.w = pk2(gv[i2][1].z, gv[i2][1].w);
      *reinterpret_cast<uint4*>(&XA[grow[i2]][gc8[i2]]) = w;
    }
  }
  __syncthreads();   // only barrier

  // ---- q segment (swapped MFMA): cols wave*48..+47; rt = wave*3 + c ----
  {
    bf16x8 aw[6][3];                 // all 18 weight frags hoisted
    #pragma unroll
    for (int ks = 0; ks < 6; ++ks)
      #pragma unroll
      for (int c = 0; c < 3; ++c)
        aw[ks][c] = wfrag(wqF, wave*3 + c, ks, lane);
    f32x4 acc[8][3];
    #pragma unroll
    for (int mt = 0; mt < 8; ++mt)
      #pragma unroll
      for (int c = 0; c < 3; ++c) acc[mt][c] = z4;
    #pragma unroll
    for (int ks = 0; ks < 6; ++ks){
      bf16x8 ax[8];
      #pragma unroll
      for (int mt = 0; mt < 8; ++mt)
        ax[mt] = *reinterpret_cast<const bf16x8*>(&XA[mt*16 + r][ks*32 + 8*g]);
      #pragma unroll
      for (int mt = 0; mt < 8; ++mt)
        #pragma unroll
        for (int c = 0; c < 3; ++c)
          acc[mt][c] = __builtin_amdgcn_mfma_f32_16x16x32_bf16(aw[ks][c], ax[mt], acc[mt][c], 0, 0, 0);
    }
    const float S = 0.17677669529663687f;
    #pragma unroll
    for (int c = 0; c < 3; ++c){
      const int ch0 = wave*48 + c*16 + 4*g;     // 4 consecutive ch (jj)
      const float4 bi = *reinterpret_cast<const float4*>(qb + ch0);
      const int chq = (ch0 & 31) >> 2;
      #pragma unroll
      for (int mt = 0; mt < 8; ++mt){
        const int tok = (mt & 3)*16 + r;        // lane r -> contiguous
        if (tok < 49){                           // skip padded rows (saves writes)
          const int u = (wi0 + (mt >> 2))*6 + (ch0 >> 5);
          uint2 t;
          t.x = pk2((acc[mt][c][0] + bi.x)*S, (acc[mt][c][1] + bi.y)*S);
          t.y = pk2((acc[mt][c][2] + bi.z)*S, (acc[mt][c][3] + bi.w)*S);
          *reinterpret_cast<uint2*>(qG + (((size_t)u*8 + chq)*64 + tok)*4) = t;
        }
      }
    }
  }

  // ---- k segment (swapped MFMA): rt = 12 + wave*3 + c ----
  {
    bf16x8 aw[6][3];
    #pragma unroll
    for (int ks = 0; ks < 6; ++ks)
      #pragma unroll
      for (int c = 0; c < 3; ++c)
        aw[ks][c] = wfrag(wqF, 12 + wave*3 + c, ks, lane);
    f32x4 acc[8][3];
    #pragma unroll
    for (int mt = 0; mt < 8; ++mt)
      #pragma unroll
      for (int c = 0; c < 3; ++c) acc[mt][c] = z4;
    #pragma unroll
    for (int ks = 0; ks < 6; ++ks){
      bf16x8 ax[8];
      #pragma unroll
      for (int mt = 0; mt < 8; ++mt)
        ax[mt] = *reinterpret_cast<const bf16x8*>(&XA[mt*16 + r][ks*32 + 8*g]);
      #pragma unroll
      for (int mt = 0; mt < 8; ++mt)
        #pragma unroll
        for (int c = 0; c < 3; ++c)
          acc[mt][c] = __builtin_amdgcn_mfma_f32_16x16x32_bf16(aw[ks][c], ax[mt], acc[mt][c], 0, 0, 0);
    }
    #pragma unroll
    for (int c = 0; c < 3; ++c){
      const int ch0 = wave*48 + c*16 + 4*g;
      const float4 bi = *reinterpret_cast<const float4*>(qb + 192 + ch0);
      const int chq = (ch0 & 31) >> 2;
      #pragma unroll
      for (int mt = 0; mt < 8; ++mt){
        const int tok = (mt & 3)*16 + r;
        if (tok < 49){                           // skip padded rows
          const int u = (wi0 + (mt >> 2))*6 + (ch0 >> 5);
          uint2 t;
          t.x = pk2(acc[mt][c][0] + bi.x, acc[mt][c][1] + bi.y);
          t.y = pk2(acc[mt][c][2] + bi.z, acc[mt][c][3] + bi.w);
          *reinterpret_cast<uint2*>(kG + (((size_t)u*8 + chq)*64 + tok)*4) = t;
        }
      }
    }
  }

  // ---- v segment (normal MFMA): rt = 24 + wave*3 + c; lane r = d ----
  // (v rows stay fully written: padded rows are MFMA operands in PV, where a
  //  stale NaN would poison the accumulator via NaN*0.)
  {
    bf16x8 bw[6][3];
    #pragma unroll
    for (int ks = 0; ks < 6; ++ks)
      #pragma unroll
      for (int c = 0; c < 3; ++c)
        bw[ks][c] = wfrag(wqF, 24 + wave*3 + c, ks, lane);
    f32x4 acc[8][3];
    #pragma unroll
    for (int mt = 0; mt < 8; ++mt)
      #pragma unroll
      for (int c = 0; c < 3; ++c) acc[mt][c] = z4;
    #pragma unroll
    for (int ks = 0; ks < 6; ++ks){
      bf16x8 ax[8];
      #pragma unroll
      for (int mt = 0; mt < 8; ++mt)
        ax[mt] = *reinterpret_cast<const bf16x8*>(&XA[mt*16 + r][ks*32 + 8*g]);
      #pragma unroll
      for (int mt = 0; mt < 8; ++mt)
        #pragma unroll
        for (int c = 0; c < 3; ++c)
          acc[mt][c] = __builtin_amdgcn_mfma_f32_16x16x32_bf16(ax[mt], bw[ks][c], acc[mt][c], 0, 0, 0);
    }
    #pragma unroll
    for (int c = 0; c < 3; ++c){
      const int ch = wave*48 + c*16 + r;        // lane r -> d (contiguous minor)
      const float bv = qb[384 + ch];
      const int d = ch & 31;
      #pragma unroll
      for (int mt = 0; mt < 8; ++mt){
        const int u = (wi0 + (mt >> 2))*6 + (ch >> 5);
        const int tokq = (mt & 3)*4 + g;        // toks 4g..4g+3 of tile (mt&3)
        uint2 t;
        t.x = pk2(acc[mt][c][0] + bv, acc[mt][c][1] + bv);
        t.y = pk2(acc[mt][c][2] + bv, acc[mt][c][3] + bv);
        *reinterpret_cast<uint2*>(vG + (((size_t)u*16 + tokq)*32 + d)*4) = t;
      }
    }
  }
}

// ---------------- B: attention (wave=head) + proj, block = 1 window ----------------
__global__ __launch_bounds__(384, 4) void attnproj_kernel(const u16* __restrict__ qG,
    const u16* __restrict__ kG, const u16* __restrict__ vG,
    const float* __restrict__ biasC, const u16* __restrict__ wpF,
    const float* __restrict__ pb, float* __restrict__ out)
{
  __shared__ u16 AO[64][200];        // attention output [tok][192]
  __shared__ u16 Psh[6][2][16][72];  // per-wave double-buffered P
  const int wi = blockIdx.x;
  const int bb = wi >> 6, wy = (wi >> 3) & 7, wx = wi & 7;
  const int tid = threadIdx.x;
  const int h = tid / 64;            // wave = head
  const int lane = tid & 63;
  const int g = lane >> 4, r = lane & 15;
  const int unit = wi*6 + h;
  const int cls = ((wy == 7) ? 2 : 0) + ((wx == 7) ? 1 : 0);
  const float* bC = biasC + ((size_t)(cls*6 + h)*64)*72;
  const f32x4 z4 = {0.f, 0.f, 0.f, 0.f};

  // unit-wide fragments, loaded once (quad-split layouts; all lane-contiguous)
  bf16x8 ak[4];
  #pragma unroll
  for (int mt = 0; mt < 4; ++mt){
    const uint2 a = *reinterpret_cast<const uint2*>(kG + (((size_t)unit*8 + 2*g    )*64 + mt*16 + r)*4);
    const uint2 b = *reinterpret_cast<const uint2*>(kG + (((size_t)unit*8 + 2*g + 1)*64 + mt*16 + r)*4);
    ak[mt] = pack8(a, b);
  }
  bf16x8 av[2][2];
  #pragma unroll
  for (int nt = 0; nt < 2; ++nt)
    #pragma unroll
    for (int k2 = 0; k2 < 2; ++k2){
      const uint2 a = *reinterpret_cast<const uint2*>(vG + (((size_t)unit*16 + k2*8 + 2*g    )*32 + nt*16 + r)*4);
      const uint2 b = *reinterpret_cast<const uint2*>(vG + (((size_t)unit*16 + k2*8 + 2*g + 1)*32 + nt*16 + r)*4);
      av[nt][k2] = pack8(a, b);
    }

  #pragma unroll 2
  for (int mt2 = 0; mt2 < 4; ++mt2){
    const int i_r = mt2*16 + r;
    const uint2 qa = *reinterpret_cast<const uint2*>(qG + (((size_t)unit*8 + 2*g    )*64 + i_r)*4);
    const uint2 qb2 = *reinterpret_cast<const uint2*>(qG + (((size_t)unit*8 + 2*g + 1)*64 + i_r)*4);
    const bf16x8 aq = pack8(qa, qb2);
    float4 bf[4];
    #pragma unroll
    for (int mt = 0; mt < 4; ++mt)
      bf[mt] = *reinterpret_cast<const float4*>(bC + (size_t)i_r*72 + mt*16 + 4*g);
    f32x4 s[4];
    #pragma unroll
    for (int mt = 0; mt < 4; ++mt)
      s[mt] = __builtin_amdgcn_mfma_f32_16x16x32_bf16(ak[mt], aq, z4, 0, 0, 0);
    float mx = -1e30f;
    #pragma unroll
    for (int mt = 0; mt < 4; ++mt)
      #pragma unroll
      for (int jj = 0; jj < 4; ++jj){
        // NaN-proof mask: padded-j columns never touch s (k rows are stale there)
        const float bfv = bf[mt][jj];
        const float t = (bfv < -1e29f) ? -1e30f : (s[mt][jj] + bfv);
        s[mt][jj] = t;
        mx = fmaxf(mx, t);
      }
    mx = fmaxf(mx, __shfl_xor(mx, 16));
    mx = fmaxf(mx, __shfl_xor(mx, 32));
    float sum = 0.f;
    #pragma unroll
    for (int mt = 0; mt < 4; ++mt)
      #pragma unroll
      for (int jj = 0; jj < 4; ++jj){
        const float p = __expf(s[mt][jj] - mx);
        s[mt][jj] = p;
        sum += p;
      }
    sum += __shfl_xor(sum, 16);
    sum += __shfl_xor(sum, 32);
    const float rs = 1.0f / sum;
    #pragma unroll
    for (int mt = 0; mt < 4; ++mt){
      uint2 pw;
      pw.x = pk2(s[mt][0]*rs, s[mt][1]*rs);
      pw.y = pk2(s[mt][2]*rs, s[mt][3]*rs);
      *reinterpret_cast<uint2*>(&Psh[h][mt2 & 1][r][16*mt + 4*g]) = pw;
    }
    f32x4 o[2] = {z4, z4};
    #pragma unroll
    for (int k2 = 0; k2 < 2; ++k2){
      const bf16x8 bp = *reinterpret_cast<const bf16x8*>(&Psh[h][mt2 & 1][r][32*k2 + 8*g]);
      #pragma unroll
      for (int nt = 0; nt < 2; ++nt)
        o[nt] = __builtin_amdgcn_mfma_f32_16x16x32_bf16(av[nt][k2], bp, o[nt], 0, 0, 0);
    }
    #pragma unroll
    for (int nt = 0; nt < 2; ++nt){
      uint2 t;
      t.x = pk2(o[nt][0], o[nt][1]);
      t.y = pk2(o[nt][2], o[nt][3]);
      *reinterpret_cast<uint2*>(&AO[i_r][h*32 + nt*16 + 4*g]) = t;
    }
  }
  __syncthreads();

  // ---- proj: 6 waves x 32 cols; A-frags from AO (LDS); weights fragment-swizzled ----
  {
    f32x4 pacc[4][2];
    #pragma unroll
    for (int mt = 0; mt < 4; ++mt){ pacc[mt][0] = z4; pacc[mt][1] = z4; }
    #pragma unroll
    for (int ks = 0; ks < 6; ++ks){
      bf16x8 a2[4];
      #pragma unroll
      for (int mt = 0; mt < 4; ++mt)
        a2[mt] = *reinterpret_cast<const bf16x8*>(&AO[mt*16 + r][ks*32 + 8*g]);
      #pragma unroll
      for (int nt = 0; nt < 2; ++nt){
        const bf16x8 bw = *reinterpret_cast<const bf16x8*>(wpF + (((size_t)(h*2 + nt)*6 + ks)*64 + lane)*8);
        #pragma unroll
        for (int mt = 0; mt < 4; ++mt)
          pacc[mt][nt] = __builtin_amdgcn_mfma_f32_16x16x32_bf16(a2[mt], bw, pacc[mt][nt], 0, 0, 0);
      }
    }
    #pragma unroll
    for (int nt = 0; nt < 2; ++nt){
      const int n = h*32 + nt*16 + r;
      const float bias = pb[n];
      #pragma unroll
      for (int mt = 0; mt < 4; ++mt)
        #pragma unroll
        for (int jj = 0; jj < 4; ++jj){
          const int tok = mt*16 + 4*g + jj;
          if (tok < 49){
            const int ty = tok/7, tx = tok%7;
            int dh = wy*7 + ty + 3; if (dh >= 56) dh -= 56;
            int dw = wx*7 + tx + 3; if (dw >= 56) dw -= 56;
            out[(size_t)((bb*56 + dh)*56 + dw)*192 + n] = pacc[mt][nt][jj] + bias;
          }
        }
    }
  }
}

extern "C" void kernel_launch(void* const* d_in, const int* in_sizes, int n_in,
                              void* d_out, int out_size, void* d_ws, size_t ws_size,
                              hipStream_t stream) {
  const float* x     = (const float*)d_in[0];
  const float* rpb   = (const float*)d_in[1];
  const float* qkvw  = (const float*)d_in[2];
  const float* qkvb  = (const float*)d_in[3];
  const float* projw = (const float*)d_in[4];
  const float* projb = (const float*)d_in[5];
  float* out = (float*)d_out;

  char* ws = (char*)d_ws;
  u16*   wqF   = (u16*)(ws);                                   // bf16 frag-swizzled [36][6][64][8]
  u16*   wpF   = (u16*)(ws + 221184);                          // bf16 frag-swizzled [12][6][64][8]
  float* biasC = (float*)(ws + 221184 + 73728);                // f32  [4][6][64][72]
  u16*   qG    = (u16*)(ws + 737280);                          // bf16 [12288][8][64][4]
  u16*   kG    = (u16*)(ws + 737280 + 1ll*50331648);           // bf16 [12288][8][64][4]
  u16*   vG    = (u16*)(ws + 737280 + 2ll*50331648);           // bf16 [12288][16][32][4]

  prep_kernel    <<<432, 256, 0, stream>>>(qkvw, projw, rpb, wqF, wpF, biasC);
  qkv_kernel     <<<1024, 256, 0, stream>>>(x, wqF, qkvb, qG, kG, vG);
  attnproj_kernel<<<2048, 384, 0, stream>>>(qG, kG, vG, biasC, wpF, projb, out);
}

// Round 17
// 126.548 us; speedup vs baseline: 1.0494x; 1.0494x over previous
//
#include <hip/hip_runtime.h>

typedef unsigned short u16;
typedef unsigned int   u32;
typedef __bf16 bf16x8 __attribute__((ext_vector_type(8)));
typedef float  f32x4  __attribute__((ext_vector_type(4)));

// Geometry (fixed): b=32, h=w=56, C=192, NH=6, hd=32, WS=7, shift=3
// 2048 windows, 49 tokens (padded to 64).
// V17 = V15 (full q/k/v stores, plain mask add) + cross-segment weight
//       prefetch: next segment's 18 weight frags issued before the current
//       segment's epilogue, pinned with ONE sched_barrier(0) per burst so the
//       epilogue stores + next LDS reads hide the L2 weight latency.

__device__ __forceinline__ u16 f2b(float f){
  return __builtin_bit_cast(u16, (__bf16)f);
}
__device__ __forceinline__ u32 pk2(float a, float b){
  return (u32)f2b(a) | ((u32)f2b(b) << 16);
}
__device__ __forceinline__ bf16x8 pack8(uint2 a, uint2 b){
  uint4 t; t.x = a.x; t.y = a.y; t.z = b.x; t.w = b.y;
  return __builtin_bit_cast(bf16x8, t);
}

__device__ __forceinline__ int coords_fn(int t){ return (t/7)*13 + (t%7); }
__device__ __forceinline__ int code_fn(int t, int wy, int wx){
  const int ty = t/7, tx = t%7;
  const int hp = wy*7 + ty, wp = wx*7 + tx;
  const int rh = (hp < 49) ? 0 : ((hp < 53) ? 1 : 2);
  const int rw = (wp < 49) ? 0 : ((wp < 53) ? 1 : 2);
  return rh*3 + rw;
}

// prep: wqF fragment-swizzled [36][6][64][8]; wpF [12][6][64][8];
//       biasC[cls][h][i][j] = rpb + (-100 shift mask) + (-1e30 j>=49)
__global__ __launch_bounds__(256) void prep_kernel(const float* __restrict__ qkvw,
                                                   const float* __restrict__ projw,
                                                   const float* __restrict__ rpb,
                                                   u16* __restrict__ wqF, u16* __restrict__ wpF,
                                                   float* __restrict__ biasC){
  const int i = blockIdx.x * 256 + threadIdx.x;   // 432*256 = 110592
  if (i < 13824){                                  // 36 tiles * 6 ks * 64 lanes
    const int f = i >> 6, l = i & 63;
    const int rt = f / 6, ks = f % 6;
    const int g = l >> 4, r = l & 15;
    const float* src = qkvw + (size_t)(rt*16 + r)*192 + ks*32 + 8*g;
    const float4 a = *reinterpret_cast<const float4*>(src);
    const float4 b = *reinterpret_cast<const float4*>(src + 4);
    uint4 w;
    w.x = pk2(a.x, a.y); w.y = pk2(a.z, a.w);
    w.z = pk2(b.x, b.y); w.w = pk2(b.z, b.w);
    *reinterpret_cast<uint4*>(wqF + (size_t)i*8) = w;
  }
  if (i < 4608){                                   // 12 tiles * 6 ks * 64 lanes
    const int f = i >> 6, l = i & 63;
    const int rt = f / 6, ks = f % 6;
    const int g = l >> 4, r = l & 15;
    const float* src = projw + (size_t)(rt*16 + r)*192 + ks*32 + 8*g;
    const float4 a = *reinterpret_cast<const float4*>(src);
    const float4 b = *reinterpret_cast<const float4*>(src + 4);
    uint4 w;
    w.x = pk2(a.x, a.y); w.y = pk2(a.z, a.w);
    w.z = pk2(b.x, b.y); w.w = pk2(b.z, b.w);
    *reinterpret_cast<uint4*>(wpF + (size_t)i*8) = w;
  }
  {
    const int cls = i / 27648, rem = i % 27648;
    const int h = rem / 4608, rem2 = rem % 4608;
    const int ii = rem2 / 72, j = rem2 % 72;
    const int wyR = (cls & 2) ? 7 : 0, wxR = (cls & 1) ? 7 : 0;
    float v = -1e30f;
    if (j < 49){
      const int icl = (ii > 48) ? 48 : ii;
      v = rpb[(coords_fn(icl) + coords_fn(48 - j))*6 + h];
      if (code_fn(icl, wyR, wxR) != code_fn(j, wyR, wxR)) v -= 100.0f;
    }
    biasC[i] = v;
  }
}

__device__ __forceinline__ bf16x8 wfrag(const u16* __restrict__ W, int rt, int ks, int lane){
  return *reinterpret_cast<const bf16x8*>(W + ((size_t)(rt*6 + ks)*64 + lane)*8);
}

// ---------------- A: roll + gather + QKV GEMM (2 windows/block) ----------------
__global__ __launch_bounds__(256, 2) void qkv_kernel(const float* __restrict__ x,
    const u16* __restrict__ wqF, const float* __restrict__ qb,
    u16* __restrict__ qG, u16* __restrict__ kG, u16* __restrict__ vG)
{
  __shared__ u16 XA[128][200];       // 2 windows x 64 tokens x 192ch
  const int wi0 = blockIdx.x * 2;    // windows wi0, wi0+1 (same bb, same wy)
  const int bb = wi0 >> 6, wy = (wi0 >> 3) & 7;
  const int tid = threadIdx.x;
  const int wave = tid >> 6, lane = tid & 63;
  const int g = lane >> 4, r = lane & 15;
  const f32x4 z4 = {0.f, 0.f, 0.f, 0.f};

  // gather: 2 halves x 6 chunks/thread of 16 bf16 (loads hoisted per half)
  #pragma unroll
  for (int half = 0; half < 2; ++half){
    float4 gv[6][2];
    int grow[6], gc8[6];
    #pragma unroll
    for (int i2 = 0; i2 < 6; ++i2){
      const int idx = half*1536 + i2*256 + tid;   // < 3072 = 128*24
      const int row = idx / 24, c8 = (idx % 24) * 8;
      grow[i2] = row; gc8[i2] = c8;
      const int rl = row & 63;
      const int wx = (wi0 + (row >> 6)) & 7;
      if (rl < 49){
        const int ty = rl / 7, tx = rl % 7;
        int sh = wy*7 + ty + 3; if (sh >= 56) sh -= 56;
        int sw = wx*7 + tx + 3; if (sw >= 56) sw -= 56;
        const float* src = x + (size_t)(((bb*56 + sh)*56 + sw))*192 + c8;
        gv[i2][0] = *reinterpret_cast<const float4*>(src);
        gv[i2][1] = *reinterpret_cast<const float4*>(src + 4);
      } else {
        gv[i2][0] = make_float4(0.f,0.f,0.f,0.f);
        gv[i2][1] = make_float4(0.f,0.f,0.f,0.f);
      }
    }
    #pragma unroll
    for (int i2 = 0; i2 < 6; ++i2){
      uint4 w;
      w.x = pk2(gv[i2][0].x, gv[i2][0].y);
      w.y = pk2(gv[i2][0].z, gv[i2][0].w);
      w.z = pk2(gv[i2][1].x, gv[i2][1].y);
      w.w = pk2(gv[i2][1].z, gv[i2][1].w);
      *reinterpret_cast<uint4*>(&XA[grow[i2]][gc8[i2]]) = w;
    }
  }
  __syncthreads();   // only barrier

  bf16x8 awq[6][3], awk[6][3], awv[6][3];
  #pragma unroll
  for (int ks = 0; ks < 6; ++ks)
    #pragma unroll
    for (int c = 0; c < 3; ++c)
      awq[ks][c] = wfrag(wqF, wave*3 + c, ks, lane);

  // ---- q segment (swapped MFMA): cols wave*48..+47 ----
  {
    f32x4 acc[8][3];
    #pragma unroll
    for (int mt = 0; mt < 8; ++mt)
      #pragma unroll
      for (int c = 0; c < 3; ++c) acc[mt][c] = z4;
    #pragma unroll
    for (int ks = 0; ks < 6; ++ks){
      bf16x8 ax[8];
      #pragma unroll
      for (int mt = 0; mt < 8; ++mt)
        ax[mt] = *reinterpret_cast<const bf16x8*>(&XA[mt*16 + r][ks*32 + 8*g]);
      #pragma unroll
      for (int mt = 0; mt < 8; ++mt)
        #pragma unroll
        for (int c = 0; c < 3; ++c)
          acc[mt][c] = __builtin_amdgcn_mfma_f32_16x16x32_bf16(awq[ks][c], ax[mt], acc[mt][c], 0, 0, 0);
    }
    // prefetch k-segment weights; pin so the epilogue + k LDS reads hide them
    #pragma unroll
    for (int ks = 0; ks < 6; ++ks)
      #pragma unroll
      for (int c = 0; c < 3; ++c)
        awk[ks][c] = wfrag(wqF, 12 + wave*3 + c, ks, lane);
    __builtin_amdgcn_sched_barrier(0);

    const float S = 0.17677669529663687f;
    #pragma unroll
    for (int c = 0; c < 3; ++c){
      const int ch0 = wave*48 + c*16 + 4*g;     // 4 consecutive ch (jj)
      const float4 bi = *reinterpret_cast<const float4*>(qb + ch0);
      const int chq = (ch0 & 31) >> 2;
      #pragma unroll
      for (int mt = 0; mt < 8; ++mt){
        const int u = (wi0 + (mt >> 2))*6 + (ch0 >> 5);
        const int tok = (mt & 3)*16 + r;        // lane r -> contiguous
        uint2 t;
        t.x = pk2((acc[mt][c][0] + bi.x)*S, (acc[mt][c][1] + bi.y)*S);
        t.y = pk2((acc[mt][c][2] + bi.z)*S, (acc[mt][c][3] + bi.w)*S);
        *reinterpret_cast<uint2*>(qG + (((size_t)u*8 + chq)*64 + tok)*4) = t;
      }
    }
  }

  // ---- k segment (swapped MFMA) ----
  {
    f32x4 acc[8][3];
    #pragma unroll
    for (int mt = 0; mt < 8; ++mt)
      #pragma unroll
      for (int c = 0; c < 3; ++c) acc[mt][c] = z4;
    #pragma unroll
    for (int ks = 0; ks < 6; ++ks){
      bf16x8 ax[8];
      #pragma unroll
      for (int mt = 0; mt < 8; ++mt)
        ax[mt] = *reinterpret_cast<const bf16x8*>(&XA[mt*16 + r][ks*32 + 8*g]);
      #pragma unroll
      for (int mt = 0; mt < 8; ++mt)
        #pragma unroll
        for (int c = 0; c < 3; ++c)
          acc[mt][c] = __builtin_amdgcn_mfma_f32_16x16x32_bf16(awk[ks][c], ax[mt], acc[mt][c], 0, 0, 0);
    }
    // prefetch v-segment weights; pin
    #pragma unroll
    for (int ks = 0; ks < 6; ++ks)
      #pragma unroll
      for (int c = 0; c < 3; ++c)
        awv[ks][c] = wfrag(wqF, 24 + wave*3 + c, ks, lane);
    __builtin_amdgcn_sched_barrier(0);

    #pragma unroll
    for (int c = 0; c < 3; ++c){
      const int ch0 = wave*48 + c*16 + 4*g;
      const float4 bi = *reinterpret_cast<const float4*>(qb + 192 + ch0);
      const int chq = (ch0 & 31) >> 2;
      #pragma unroll
      for (int mt = 0; mt < 8; ++mt){
        const int u = (wi0 + (mt >> 2))*6 + (ch0 >> 5);
        const int tok = (mt & 3)*16 + r;
        uint2 t;
        t.x = pk2(acc[mt][c][0] + bi.x, acc[mt][c][1] + bi.y);
        t.y = pk2(acc[mt][c][2] + bi.z, acc[mt][c][3] + bi.w);
        *reinterpret_cast<uint2*>(kG + (((size_t)u*8 + chq)*64 + tok)*4) = t;
      }
    }
  }

  // ---- v segment (normal MFMA): lane r = d ----
  {
    f32x4 acc[8][3];
    #pragma unroll
    for (int mt = 0; mt < 8; ++mt)
      #pragma unroll
      for (int c = 0; c < 3; ++c) acc[mt][c] = z4;
    #pragma unroll
    for (int ks = 0; ks < 6; ++ks){
      bf16x8 ax[8];
      #pragma unroll
      for (int mt = 0; mt < 8; ++mt)
        ax[mt] = *reinterpret_cast<const bf16x8*>(&XA[mt*16 + r][ks*32 + 8*g]);
      #pragma unroll
      for (int mt = 0; mt < 8; ++mt)
        #pragma unroll
        for (int c = 0; c < 3; ++c)
          acc[mt][c] = __builtin_amdgcn_mfma_f32_16x16x32_bf16(ax[mt], awv[ks][c], acc[mt][c], 0, 0, 0);
    }
    #pragma unroll
    for (int c = 0; c < 3; ++c){
      const int ch = wave*48 + c*16 + r;        // lane r -> d (contiguous minor)
      const float bv = qb[384 + ch];
      const int d = ch & 31;
      #pragma unroll
      for (int mt = 0; mt < 8; ++mt){
        const int u = (wi0 + (mt >> 2))*6 + (ch >> 5);
        const int tokq = (mt & 3)*4 + g;        // toks 4g..4g+3 of tile (mt&3)
        uint2 t;
        t.x = pk2(acc[mt][c][0] + bv, acc[mt][c][1] + bv);
        t.y = pk2(acc[mt][c][2] + bv, acc[mt][c][3] + bv);
        *reinterpret_cast<uint2*>(vG + (((size_t)u*16 + tokq)*32 + d)*4) = t;
      }
    }
  }
}

// ---------------- B: attention (wave=head) + proj, block = 1 window ----------------
__global__ __launch_bounds__(384, 4) void attnproj_kernel(const u16* __restrict__ qG,
    const u16* __restrict__ kG, const u16* __restrict__ vG,
    const float* __restrict__ biasC, const u16* __restrict__ wpF,
    const float* __restrict__ pb, float* __restrict__ out)
{
  __shared__ u16 AO[64][200];        // attention output [tok][192]
  __shared__ u16 Psh[6][2][16][72];  // per-wave double-buffered P
  const int wi = blockIdx.x;
  const int bb = wi >> 6, wy = (wi >> 3) & 7, wx = wi & 7;
  const int tid = threadIdx.x;
  const int h = tid / 64;            // wave = head
  const int lane = tid & 63;
  const int g = lane >> 4, r = lane & 15;
  const int unit = wi*6 + h;
  const int cls = ((wy == 7) ? 2 : 0) + ((wx == 7) ? 1 : 0);
  const float* bC = biasC + ((size_t)(cls*6 + h)*64)*72;
  const f32x4 z4 = {0.f, 0.f, 0.f, 0.f};

  // unit-wide fragments, loaded once (quad-split layouts; all lane-contiguous)
  bf16x8 ak[4];
  #pragma unroll
  for (int mt = 0; mt < 4; ++mt){
    const uint2 a = *reinterpret_cast<const uint2*>(kG + (((size_t)unit*8 + 2*g    )*64 + mt*16 + r)*4);
    const uint2 b = *reinterpret_cast<const uint2*>(kG + (((size_t)unit*8 + 2*g + 1)*64 + mt*16 + r)*4);
    ak[mt] = pack8(a, b);
  }
  bf16x8 av[2][2];
  #pragma unroll
  for (int nt = 0; nt < 2; ++nt)
    #pragma unroll
    for (int k2 = 0; k2 < 2; ++k2){
      const uint2 a = *reinterpret_cast<const uint2*>(vG + (((size_t)unit*16 + k2*8 + 2*g    )*32 + nt*16 + r)*4);
      const uint2 b = *reinterpret_cast<const uint2*>(vG + (((size_t)unit*16 + k2*8 + 2*g + 1)*32 + nt*16 + r)*4);
      av[nt][k2] = pack8(a, b);
    }

  #pragma unroll 2
  for (int mt2 = 0; mt2 < 4; ++mt2){
    const int i_r = mt2*16 + r;
    const uint2 qa = *reinterpret_cast<const uint2*>(qG + (((size_t)unit*8 + 2*g    )*64 + i_r)*4);
    const uint2 qb2 = *reinterpret_cast<const uint2*>(qG + (((size_t)unit*8 + 2*g + 1)*64 + i_r)*4);
    const bf16x8 aq = pack8(qa, qb2);
    float4 bf[4];
    #pragma unroll
    for (int mt = 0; mt < 4; ++mt)
      bf[mt] = *reinterpret_cast<const float4*>(bC + (size_t)i_r*72 + mt*16 + 4*g);
    f32x4 s[4];
    #pragma unroll
    for (int mt = 0; mt < 4; ++mt)
      s[mt] = __builtin_amdgcn_mfma_f32_16x16x32_bf16(ak[mt], aq, z4, 0, 0, 0);
    float mx = -1e30f;
    #pragma unroll
    for (int mt = 0; mt < 4; ++mt)
      #pragma unroll
      for (int jj = 0; jj < 4; ++jj){
        const float t = s[mt][jj] + bf[mt][jj];
        s[mt][jj] = t;
        mx = fmaxf(mx, t);
      }
    mx = fmaxf(mx, __shfl_xor(mx, 16));
    mx = fmaxf(mx, __shfl_xor(mx, 32));
    float sum = 0.f;
    #pragma unroll
    for (int mt = 0; mt < 4; ++mt)
      #pragma unroll
      for (int jj = 0; jj < 4; ++jj){
        const float p = __expf(s[mt][jj] - mx);
        s[mt][jj] = p;
        sum += p;
      }
    sum += __shfl_xor(sum, 16);
    sum += __shfl_xor(sum, 32);
    const float rs = 1.0f / sum;
    #pragma unroll
    for (int mt = 0; mt < 4; ++mt){
      uint2 pw;
      pw.x = pk2(s[mt][0]*rs, s[mt][1]*rs);
      pw.y = pk2(s[mt][2]*rs, s[mt][3]*rs);
      *reinterpret_cast<uint2*>(&Psh[h][mt2 & 1][r][16*mt + 4*g]) = pw;
    }
    f32x4 o[2] = {z4, z4};
    #pragma unroll
    for (int k2 = 0; k2 < 2; ++k2){
      const bf16x8 bp = *reinterpret_cast<const bf16x8*>(&Psh[h][mt2 & 1][r][32*k2 + 8*g]);
      #pragma unroll
      for (int nt = 0; nt < 2; ++nt)
        o[nt] = __builtin_amdgcn_mfma_f32_16x16x32_bf16(av[nt][k2], bp, o[nt], 0, 0, 0);
    }
    #pragma unroll
    for (int nt = 0; nt < 2; ++nt){
      uint2 t;
      t.x = pk2(o[nt][0], o[nt][1]);
      t.y = pk2(o[nt][2], o[nt][3]);
      *reinterpret_cast<uint2*>(&AO[i_r][h*32 + nt*16 + 4*g]) = t;
    }
  }
  __syncthreads();

  // ---- proj: 6 waves x 32 cols; A-frags from AO (LDS); weights fragment-swizzled ----
  {
    f32x4 pacc[4][2];
    #pragma unroll
    for (int mt = 0; mt < 4; ++mt){ pacc[mt][0] = z4; pacc[mt][1] = z4; }
    #pragma unroll
    for (int ks = 0; ks < 6; ++ks){
      bf16x8 a2[4];
      #pragma unroll
      for (int mt = 0; mt < 4; ++mt)
        a2[mt] = *reinterpret_cast<const bf16x8*>(&AO[mt*16 + r][ks*32 + 8*g]);
      #pragma unroll
      for (int nt = 0; nt < 2; ++nt){
        const bf16x8 bw = *reinterpret_cast<const bf16x8*>(wpF + (((size_t)(h*2 + nt)*6 + ks)*64 + lane)*8);
        #pragma unroll
        for (int mt = 0; mt < 4; ++mt)
          pacc[mt][nt] = __builtin_amdgcn_mfma_f32_16x16x32_bf16(a2[mt], bw, pacc[mt][nt], 0, 0, 0);
      }
    }
    #pragma unroll
    for (int nt = 0; nt < 2; ++nt){
      const int n = h*32 + nt*16 + r;
      const float bias = pb[n];
      #pragma unroll
      for (int mt = 0; mt < 4; ++mt)
        #pragma unroll
        for (int jj = 0; jj < 4; ++jj){
          const int tok = mt*16 + 4*g + jj;
          if (tok < 49){
            const int ty = tok/7, tx = tok%7;
            int dh = wy*7 + ty + 3; if (dh >= 56) dh -= 56;
            int dw = wx*7 + tx + 3; if (dw >= 56) dw -= 56;
            out[(size_t)((bb*56 + dh)*56 + dw)*192 + n] = pacc[mt][nt][jj] + bias;
          }
        }
    }
  }
}

extern "C" void kernel_launch(void* const* d_in, const int* in_sizes, int n_in,
                              void* d_out, int out_size, void* d_ws, size_t ws_size,
                              hipStream_t stream) {
  const float* x     = (const float*)d_in[0];
  const float* rpb   = (const float*)d_in[1];
  const float* qkvw  = (const float*)d_in[2];
  const float* qkvb  = (const float*)d_in[3];
  const float* projw = (const float*)d_in[4];
  const float* projb = (const float*)d_in[5];
  float* out = (float*)d_out;

  char* ws = (char*)d_ws;
  u16*   wqF   = (u16*)(ws);                                   // bf16 frag-swizzled [36][6][64][8]
  u16*   wpF   = (u16*)(ws + 221184);                          // bf16 frag-swizzled [12][6][64][8]
  float* biasC = (float*)(ws + 221184 + 73728);                // f32  [4][6][64][72]
  u16*   qG    = (u16*)(ws + 737280);                          // bf16 [12288][8][64][4]
  u16*   kG    = (u16*)(ws + 737280 + 1ll*50331648);           // bf16 [12288][8][64][4]
  u16*   vG    = (u16*)(ws + 737280 + 2ll*50331648);           // bf16 [12288][16][32][4]

  prep_kernel    <<<432, 256, 0, stream>>>(qkvw, projw, rpb, wqF, wpF, biasC);
  qkv_kernel     <<<1024, 256, 0, stream>>>(x, wqF, qkvb, qG, kG, vG);
  attnproj_kernel<<<2048, 384, 0, stream>>>(qG, kG, vG, biasC, wpF, projb, out);
}

// Round 18
// 114.141 us; speedup vs baseline: 1.1635x; 1.1087x over previous
//
#include <hip/hip_runtime.h>

typedef unsigned short u16;
typedef unsigned int   u32;
typedef __bf16 bf16x8 __attribute__((ext_vector_type(8)));
typedef float  f32x4  __attribute__((ext_vector_type(4)));

// Geometry (fixed): b=32, h=w=56, C=192, NH=6, hd=32, WS=7, shift=3
// 2048 windows, 49 tokens (padded to 64).
// V18 = exact revert to V15 (best measured: 114.8 us total; qkv 70, attnproj 37).
//   qkv: 2 windows/block, launch_bounds(256,2), wqF fragment-swizzled weights
//        (hoisted per segment), quad-split coalesced q/k/v stores.
//   attnproj: wave=head, quad-split loads, biasC folded mask, wpF weights.
//   R16 (store predication) and R17 (prefetch+pin) both regressed and are out.

__device__ __forceinline__ u16 f2b(float f){
  return __builtin_bit_cast(u16, (__bf16)f);
}
__device__ __forceinline__ u32 pk2(float a, float b){
  return (u32)f2b(a) | ((u32)f2b(b) << 16);
}
__device__ __forceinline__ bf16x8 pack8(uint2 a, uint2 b){
  uint4 t; t.x = a.x; t.y = a.y; t.z = b.x; t.w = b.y;
  return __builtin_bit_cast(bf16x8, t);
}

__device__ __forceinline__ int coords_fn(int t){ return (t/7)*13 + (t%7); }
__device__ __forceinline__ int code_fn(int t, int wy, int wx){
  const int ty = t/7, tx = t%7;
  const int hp = wy*7 + ty, wp = wx*7 + tx;
  const int rh = (hp < 49) ? 0 : ((hp < 53) ? 1 : 2);
  const int rw = (wp < 49) ? 0 : ((wp < 53) ? 1 : 2);
  return rh*3 + rw;
}

// prep: wqF fragment-swizzled [36][6][64][8]; wpF [12][6][64][8];
//       biasC[cls][h][i][j] = rpb + (-100 shift mask) + (-1e30 j>=49)
__global__ __launch_bounds__(256) void prep_kernel(const float* __restrict__ qkvw,
                                                   const float* __restrict__ projw,
                                                   const float* __restrict__ rpb,
                                                   u16* __restrict__ wqF, u16* __restrict__ wpF,
                                                   float* __restrict__ biasC){
  const int i = blockIdx.x * 256 + threadIdx.x;   // 432*256 = 110592
  if (i < 13824){                                  // 36 tiles * 6 ks * 64 lanes
    const int f = i >> 6, l = i & 63;
    const int rt = f / 6, ks = f % 6;
    const int g = l >> 4, r = l & 15;
    const float* src = qkvw + (size_t)(rt*16 + r)*192 + ks*32 + 8*g;
    const float4 a = *reinterpret_cast<const float4*>(src);
    const float4 b = *reinterpret_cast<const float4*>(src + 4);
    uint4 w;
    w.x = pk2(a.x, a.y); w.y = pk2(a.z, a.w);
    w.z = pk2(b.x, b.y); w.w = pk2(b.z, b.w);
    *reinterpret_cast<uint4*>(wqF + (size_t)i*8) = w;
  }
  if (i < 4608){                                   // 12 tiles * 6 ks * 64 lanes
    const int f = i >> 6, l = i & 63;
    const int rt = f / 6, ks = f % 6;
    const int g = l >> 4, r = l & 15;
    const float* src = projw + (size_t)(rt*16 + r)*192 + ks*32 + 8*g;
    const float4 a = *reinterpret_cast<const float4*>(src);
    const float4 b = *reinterpret_cast<const float4*>(src + 4);
    uint4 w;
    w.x = pk2(a.x, a.y); w.y = pk2(a.z, a.w);
    w.z = pk2(b.x, b.y); w.w = pk2(b.z, b.w);
    *reinterpret_cast<uint4*>(wpF + (size_t)i*8) = w;
  }
  {
    const int cls = i / 27648, rem = i % 27648;
    const int h = rem / 4608, rem2 = rem % 4608;
    const int ii = rem2 / 72, j = rem2 % 72;
    const int wyR = (cls & 2) ? 7 : 0, wxR = (cls & 1) ? 7 : 0;
    float v = -1e30f;
    if (j < 49){
      const int icl = (ii > 48) ? 48 : ii;
      v = rpb[(coords_fn(icl) + coords_fn(48 - j))*6 + h];
      if (code_fn(icl, wyR, wxR) != code_fn(j, wyR, wxR)) v -= 100.0f;
    }
    biasC[i] = v;
  }
}

__device__ __forceinline__ bf16x8 wfrag(const u16* __restrict__ W, int rt, int ks, int lane){
  return *reinterpret_cast<const bf16x8*>(W + ((size_t)(rt*6 + ks)*64 + lane)*8);
}

// ---------------- A: roll + gather + QKV GEMM (2 windows/block) ----------------
__global__ __launch_bounds__(256, 2) void qkv_kernel(const float* __restrict__ x,
    const u16* __restrict__ wqF, const float* __restrict__ qb,
    u16* __restrict__ qG, u16* __restrict__ kG, u16* __restrict__ vG)
{
  __shared__ u16 XA[128][200];       // 2 windows x 64 tokens x 192ch
  const int wi0 = blockIdx.x * 2;    // windows wi0, wi0+1 (same bb, same wy)
  const int bb = wi0 >> 6, wy = (wi0 >> 3) & 7;
  const int tid = threadIdx.x;
  const int wave = tid >> 6, lane = tid & 63;
  const int g = lane >> 4, r = lane & 15;
  const f32x4 z4 = {0.f, 0.f, 0.f, 0.f};

  // gather: 2 halves x 6 chunks/thread of 16 bf16 (loads hoisted per half)
  #pragma unroll
  for (int half = 0; half < 2; ++half){
    float4 gv[6][2];
    int grow[6], gc8[6];
    #pragma unroll
    for (int i2 = 0; i2 < 6; ++i2){
      const int idx = half*1536 + i2*256 + tid;   // < 3072 = 128*24
      const int row = idx / 24, c8 = (idx % 24) * 8;
      grow[i2] = row; gc8[i2] = c8;
      const int rl = row & 63;
      const int wx = (wi0 + (row >> 6)) & 7;
      if (rl < 49){
        const int ty = rl / 7, tx = rl % 7;
        int sh = wy*7 + ty + 3; if (sh >= 56) sh -= 56;
        int sw = wx*7 + tx + 3; if (sw >= 56) sw -= 56;
        const float* src = x + (size_t)(((bb*56 + sh)*56 + sw))*192 + c8;
        gv[i2][0] = *reinterpret_cast<const float4*>(src);
        gv[i2][1] = *reinterpret_cast<const float4*>(src + 4);
      } else {
        gv[i2][0] = make_float4(0.f,0.f,0.f,0.f);
        gv[i2][1] = make_float4(0.f,0.f,0.f,0.f);
      }
    }
    #pragma unroll
    for (int i2 = 0; i2 < 6; ++i2){
      uint4 w;
      w.x = pk2(gv[i2][0].x, gv[i2][0].y);
      w.y = pk2(gv[i2][0].z, gv[i2][0].w);
      w.z = pk2(gv[i2][1].x, gv[i2][1].y);
      w.w = pk2(gv[i2][1].z, gv[i2][1].w);
      *reinterpret_cast<uint4*>(&XA[grow[i2]][gc8[i2]]) = w;
    }
  }
  __syncthreads();   // only barrier

  // ---- q segment (swapped MFMA): cols wave*48..+47; rt = wave*3 + c ----
  {
    bf16x8 aw[6][3];                 // all 18 weight frags hoisted
    #pragma unroll
    for (int ks = 0; ks < 6; ++ks)
      #pragma unroll
      for (int c = 0; c < 3; ++c)
        aw[ks][c] = wfrag(wqF, wave*3 + c, ks, lane);
    f32x4 acc[8][3];
    #pragma unroll
    for (int mt = 0; mt < 8; ++mt)
      #pragma unroll
      for (int c = 0; c < 3; ++c) acc[mt][c] = z4;
    #pragma unroll
    for (int ks = 0; ks < 6; ++ks){
      bf16x8 ax[8];
      #pragma unroll
      for (int mt = 0; mt < 8; ++mt)
        ax[mt] = *reinterpret_cast<const bf16x8*>(&XA[mt*16 + r][ks*32 + 8*g]);
      #pragma unroll
      for (int mt = 0; mt < 8; ++mt)
        #pragma unroll
        for (int c = 0; c < 3; ++c)
          acc[mt][c] = __builtin_amdgcn_mfma_f32_16x16x32_bf16(aw[ks][c], ax[mt], acc[mt][c], 0, 0, 0);
    }
    const float S = 0.17677669529663687f;
    #pragma unroll
    for (int c = 0; c < 3; ++c){
      const int ch0 = wave*48 + c*16 + 4*g;     // 4 consecutive ch (jj)
      const float4 bi = *reinterpret_cast<const float4*>(qb + ch0);
      const int chq = (ch0 & 31) >> 2;
      #pragma unroll
      for (int mt = 0; mt < 8; ++mt){
        const int u = (wi0 + (mt >> 2))*6 + (ch0 >> 5);
        const int tok = (mt & 3)*16 + r;        // lane r -> contiguous
        uint2 t;
        t.x = pk2((acc[mt][c][0] + bi.x)*S, (acc[mt][c][1] + bi.y)*S);
        t.y = pk2((acc[mt][c][2] + bi.z)*S, (acc[mt][c][3] + bi.w)*S);
        *reinterpret_cast<uint2*>(qG + (((size_t)u*8 + chq)*64 + tok)*4) = t;
      }
    }
  }

  // ---- k segment (swapped MFMA): rt = 12 + wave*3 + c ----
  {
    bf16x8 aw[6][3];
    #pragma unroll
    for (int ks = 0; ks < 6; ++ks)
      #pragma unroll
      for (int c = 0; c < 3; ++c)
        aw[ks][c] = wfrag(wqF, 12 + wave*3 + c, ks, lane);
    f32x4 acc[8][3];
    #pragma unroll
    for (int mt = 0; mt < 8; ++mt)
      #pragma unroll
      for (int c = 0; c < 3; ++c) acc[mt][c] = z4;
    #pragma unroll
    for (int ks = 0; ks < 6; ++ks){
      bf16x8 ax[8];
      #pragma unroll
      for (int mt = 0; mt < 8; ++mt)
        ax[mt] = *reinterpret_cast<const bf16x8*>(&XA[mt*16 + r][ks*32 + 8*g]);
      #pragma unroll
      for (int mt = 0; mt < 8; ++mt)
        #pragma unroll
        for (int c = 0; c < 3; ++c)
          acc[mt][c] = __builtin_amdgcn_mfma_f32_16x16x32_bf16(aw[ks][c], ax[mt], acc[mt][c], 0, 0, 0);
    }
    #pragma unroll
    for (int c = 0; c < 3; ++c){
      const int ch0 = wave*48 + c*16 + 4*g;
      const float4 bi = *reinterpret_cast<const float4*>(qb + 192 + ch0);
      const int chq = (ch0 & 31) >> 2;
      #pragma unroll
      for (int mt = 0; mt < 8; ++mt){
        const int u = (wi0 + (mt >> 2))*6 + (ch0 >> 5);
        const int tok = (mt & 3)*16 + r;
        uint2 t;
        t.x = pk2(acc[mt][c][0] + bi.x, acc[mt][c][1] + bi.y);
        t.y = pk2(acc[mt][c][2] + bi.z, acc[mt][c][3] + bi.w);
        *reinterpret_cast<uint2*>(kG + (((size_t)u*8 + chq)*64 + tok)*4) = t;
      }
    }
  }

  // ---- v segment (normal MFMA): rt = 24 + wave*3 + c; lane r = d ----
  {
    bf16x8 bw[6][3];
    #pragma unroll
    for (int ks = 0; ks < 6; ++ks)
      #pragma unroll
      for (int c = 0; c < 3; ++c)
        bw[ks][c] = wfrag(wqF, 24 + wave*3 + c, ks, lane);
    f32x4 acc[8][3];
    #pragma unroll
    for (int mt = 0; mt < 8; ++mt)
      #pragma unroll
      for (int c = 0; c < 3; ++c) acc[mt][c] = z4;
    #pragma unroll
    for (int ks = 0; ks < 6; ++ks){
      bf16x8 ax[8];
      #pragma unroll
      for (int mt = 0; mt < 8; ++mt)
        ax[mt] = *reinterpret_cast<const bf16x8*>(&XA[mt*16 + r][ks*32 + 8*g]);
      #pragma unroll
      for (int mt = 0; mt < 8; ++mt)
        #pragma unroll
        for (int c = 0; c < 3; ++c)
          acc[mt][c] = __builtin_amdgcn_mfma_f32_16x16x32_bf16(ax[mt], bw[ks][c], acc[mt][c], 0, 0, 0);
    }
    #pragma unroll
    for (int c = 0; c < 3; ++c){
      const int ch = wave*48 + c*16 + r;        // lane r -> d (contiguous minor)
      const float bv = qb[384 + ch];
      const int d = ch & 31;
      #pragma unroll
      for (int mt = 0; mt < 8; ++mt){
        const int u = (wi0 + (mt >> 2))*6 + (ch >> 5);
        const int tokq = (mt & 3)*4 + g;        // toks 4g..4g+3 of tile (mt&3)
        uint2 t;
        t.x = pk2(acc[mt][c][0] + bv, acc[mt][c][1] + bv);
        t.y = pk2(acc[mt][c][2] + bv, acc[mt][c][3] + bv);
        *reinterpret_cast<uint2*>(vG + (((size_t)u*16 + tokq)*32 + d)*4) = t;
      }
    }
  }
}

// ---------------- B: attention (wave=head) + proj, block = 1 window ----------------
__global__ __launch_bounds__(384, 4) void attnproj_kernel(const u16* __restrict__ qG,
    const u16* __restrict__ kG, const u16* __restrict__ vG,
    const float* __restrict__ biasC, const u16* __restrict__ wpF,
    const float* __restrict__ pb, float* __restrict__ out)
{
  __shared__ u16 AO[64][200];        // attention output [tok][192]
  __shared__ u16 Psh[6][2][16][72];  // per-wave double-buffered P
  const int wi = blockIdx.x;
  const int bb = wi >> 6, wy = (wi >> 3) & 7, wx = wi & 7;
  const int tid = threadIdx.x;
  const int h = tid / 64;            // wave = head
  const int lane = tid & 63;
  const int g = lane >> 4, r = lane & 15;
  const int unit = wi*6 + h;
  const int cls = ((wy == 7) ? 2 : 0) + ((wx == 7) ? 1 : 0);
  const float* bC = biasC + ((size_t)(cls*6 + h)*64)*72;
  const f32x4 z4 = {0.f, 0.f, 0.f, 0.f};

  // unit-wide fragments, loaded once (quad-split layouts; all lane-contiguous)
  bf16x8 ak[4];
  #pragma unroll
  for (int mt = 0; mt < 4; ++mt){
    const uint2 a = *reinterpret_cast<const uint2*>(kG + (((size_t)unit*8 + 2*g    )*64 + mt*16 + r)*4);
    const uint2 b = *reinterpret_cast<const uint2*>(kG + (((size_t)unit*8 + 2*g + 1)*64 + mt*16 + r)*4);
    ak[mt] = pack8(a, b);
  }
  bf16x8 av[2][2];
  #pragma unroll
  for (int nt = 0; nt < 2; ++nt)
    #pragma unroll
    for (int k2 = 0; k2 < 2; ++k2){
      const uint2 a = *reinterpret_cast<const uint2*>(vG + (((size_t)unit*16 + k2*8 + 2*g    )*32 + nt*16 + r)*4);
      const uint2 b = *reinterpret_cast<const uint2*>(vG + (((size_t)unit*16 + k2*8 + 2*g + 1)*32 + nt*16 + r)*4);
      av[nt][k2] = pack8(a, b);
    }

  #pragma unroll 2
  for (int mt2 = 0; mt2 < 4; ++mt2){
    const int i_r = mt2*16 + r;
    const uint2 qa = *reinterpret_cast<const uint2*>(qG + (((size_t)unit*8 + 2*g    )*64 + i_r)*4);
    const uint2 qb2 = *reinterpret_cast<const uint2*>(qG + (((size_t)unit*8 + 2*g + 1)*64 + i_r)*4);
    const bf16x8 aq = pack8(qa, qb2);
    float4 bf[4];
    #pragma unroll
    for (int mt = 0; mt < 4; ++mt)
      bf[mt] = *reinterpret_cast<const float4*>(bC + (size_t)i_r*72 + mt*16 + 4*g);
    f32x4 s[4];
    #pragma unroll
    for (int mt = 0; mt < 4; ++mt)
      s[mt] = __builtin_amdgcn_mfma_f32_16x16x32_bf16(ak[mt], aq, z4, 0, 0, 0);
    float mx = -1e30f;
    #pragma unroll
    for (int mt = 0; mt < 4; ++mt)
      #pragma unroll
      for (int jj = 0; jj < 4; ++jj){
        const float t = s[mt][jj] + bf[mt][jj];
        s[mt][jj] = t;
        mx = fmaxf(mx, t);
      }
    mx = fmaxf(mx, __shfl_xor(mx, 16));
    mx = fmaxf(mx, __shfl_xor(mx, 32));
    float sum = 0.f;
    #pragma unroll
    for (int mt = 0; mt < 4; ++mt)
      #pragma unroll
      for (int jj = 0; jj < 4; ++jj){
        const float p = __expf(s[mt][jj] - mx);
        s[mt][jj] = p;
        sum += p;
      }
    sum += __shfl_xor(sum, 16);
    sum += __shfl_xor(sum, 32);
    const float rs = 1.0f / sum;
    #pragma unroll
    for (int mt = 0; mt < 4; ++mt){
      uint2 pw;
      pw.x = pk2(s[mt][0]*rs, s[mt][1]*rs);
      pw.y = pk2(s[mt][2]*rs, s[mt][3]*rs);
      *reinterpret_cast<uint2*>(&Psh[h][mt2 & 1][r][16*mt + 4*g]) = pw;
    }
    f32x4 o[2] = {z4, z4};
    #pragma unroll
    for (int k2 = 0; k2 < 2; ++k2){
      const bf16x8 bp = *reinterpret_cast<const bf16x8*>(&Psh[h][mt2 & 1][r][32*k2 + 8*g]);
      #pragma unroll
      for (int nt = 0; nt < 2; ++nt)
        o[nt] = __builtin_amdgcn_mfma_f32_16x16x32_bf16(av[nt][k2], bp, o[nt], 0, 0, 0);
    }
    #pragma unroll
    for (int nt = 0; nt < 2; ++nt){
      uint2 t;
      t.x = pk2(o[nt][0], o[nt][1]);
      t.y = pk2(o[nt][2], o[nt][3]);
      *reinterpret_cast<uint2*>(&AO[i_r][h*32 + nt*16 + 4*g]) = t;
    }
  }
  __syncthreads();

  // ---- proj: 6 waves x 32 cols; A-frags from AO (LDS); weights fragment-swizzled ----
  {
    f32x4 pacc[4][2];
    #pragma unroll
    for (int mt = 0; mt < 4; ++mt){ pacc[mt][0] = z4; pacc[mt][1] = z4; }
    #pragma unroll
    for (int ks = 0; ks < 6; ++ks){
      bf16x8 a2[4];
      #pragma unroll
      for (int mt = 0; mt < 4; ++mt)
        a2[mt] = *reinterpret_cast<const bf16x8*>(&AO[mt*16 + r][ks*32 + 8*g]);
      #pragma unroll
      for (int nt = 0; nt < 2; ++nt){
        const bf16x8 bw = *reinterpret_cast<const bf16x8*>(wpF + (((size_t)(h*2 + nt)*6 + ks)*64 + lane)*8);
        #pragma unroll
        for (int mt = 0; mt < 4; ++mt)
          pacc[mt][nt] = __builtin_amdgcn_mfma_f32_16x16x32_bf16(a2[mt], bw, pacc[mt][nt], 0, 0, 0);
      }
    }
    #pragma unroll
    for (int nt = 0; nt < 2; ++nt){
      const int n = h*32 + nt*16 + r;
      const float bias = pb[n];
      #pragma unroll
      for (int mt = 0; mt < 4; ++mt)
        #pragma unroll
        for (int jj = 0; jj < 4; ++jj){
          const int tok = mt*16 + 4*g + jj;
          if (tok < 49){
            const int ty = tok/7, tx = tok%7;
            int dh = wy*7 + ty + 3; if (dh >= 56) dh -= 56;
            int dw = wx*7 + tx + 3; if (dw >= 56) dw -= 56;
            out[(size_t)((bb*56 + dh)*56 + dw)*192 + n] = pacc[mt][nt][jj] + bias;
          }
        }
    }
  }
}

extern "C" void kernel_launch(void* const* d_in, const int* in_sizes, int n_in,
                              void* d_out, int out_size, void* d_ws, size_t ws_size,
                              hipStream_t stream) {
  const float* x     = (const float*)d_in[0];
  const float* rpb   = (const float*)d_in[1];
  const float* qkvw  = (const float*)d_in[2];
  const float* qkvb  = (const float*)d_in[3];
  const float* projw = (const float*)d_in[4];
  const float* projb = (const float*)d_in[5];
  float* out = (float*)d_out;

  char* ws = (char*)d_ws;
  u16*   wqF   = (u16*)(ws);                                   // bf16 frag-swizzled [36][6][64][8]
  u16*   wpF   = (u16*)(ws + 221184);                          // bf16 frag-swizzled [12][6][64][8]
  float* biasC = (float*)(ws + 221184 + 73728);                // f32  [4][6][64][72]
  u16*   qG    = (u16*)(ws + 737280);                          // bf16 [12288][8][64][4]
  u16*   kG    = (u16*)(ws + 737280 + 1ll*50331648);           // bf16 [12288][8][64][4]
  u16*   vG    = (u16*)(ws + 737280 + 2ll*50331648);           // bf16 [12288][16][32][4]

  prep_kernel    <<<432, 256, 0, stream>>>(qkvw, projw, rpb, wqF, wpF, biasC);
  qkv_kernel     <<<1024, 256, 0, stream>>>(x, wqF, qkvb, qG, kG, vG);
  attnproj_kernel<<<2048, 384, 0, stream>>>(qG, kG, vG, biasC, wpF, projb, out);
}